// Round 1
// 833.456 us; speedup vs baseline: 1.2172x; 1.2172x over previous
//
#include <hip/hip_runtime.h>
#include <stdint.h>

#define N_ROWS 16384   // 16 * 32 * 32
#define N_E    8192
#define EDIM   256
#define QELEMS 4194304 // 16*256*32*32
#define NBLK   64      // 8192 / 128 column blocks
#define BLKC   128
#define PITCH  72      // LDS row pitch in shorts: 144B = 9x16B granules (coprime w/ 8) -> conflict-free b128

using f32x4  = __attribute__((ext_vector_type(4))) float;
using bf16x8 = __attribute__((ext_vector_type(8))) short;

// ---------- helpers ----------
__device__ __forceinline__ unsigned int f2ord(float f) {
    unsigned int u = __float_as_uint(f);
    return (u & 0x80000000u) ? ~u : (u | 0x80000000u);
}
__device__ __forceinline__ float ord2f(unsigned int o) {
    unsigned int u = (o & 0x80000000u) ? (o & 0x7fffffffu) : ~o;
    return __uint_as_float(u);
}
__device__ __forceinline__ unsigned long long shfl_xor_u64(unsigned long long v, int m) {
    int lo = __shfl_xor((int)(unsigned int)(v & 0xffffffffull), m);
    int hi = __shfl_xor((int)(unsigned int)(v >> 32), m);
    return ((unsigned long long)(unsigned int)hi << 32) | (unsigned long long)(unsigned int)lo;
}
// round-to-nearest-even float -> bf16 bits (inputs finite, no NaN)
__device__ __forceinline__ unsigned short f2bf(float f) {
    unsigned int u = __float_as_uint(f);
    u += 0x7fffu + ((u >> 16) & 1u);
    return (unsigned short)(u >> 16);
}
__device__ __forceinline__ float bf2f(unsigned short h) {
    return __uint_as_float((unsigned int)h << 16);
}
__device__ __forceinline__ void cvt_split4(float4 v, ushort4* H, ushort4* L) {
    unsigned short h0 = f2bf(v.x), h1 = f2bf(v.y), h2 = f2bf(v.z), h3 = f2bf(v.w);
    H->x = h0; H->y = h1; H->z = h2; H->w = h3;
    L->x = f2bf(v.x - bf2f(h0));
    L->y = f2bf(v.y - bf2f(h1));
    L->z = f2bf(v.z - bf2f(h2));
    L->w = f2bf(v.w - bf2f(h3));
}

// ---------- kernel 1: row norms (UNCHANGED math -> bit-identical Crow) + margin ----------
__global__ void vq_rownorm(const float* __restrict__ z, float* __restrict__ Crow,
                           float* __restrict__ Mrow) {
    int r = blockIdx.x * blockDim.x + threadIdx.x;
    if (r >= N_ROWS) return;
    int b = r >> 10, hw = r & 1023;
    const float* p = z + ((size_t)b << 18) + hw;
    double s0 = 0.0, s1 = 0.0, s2 = 0.0, s3 = 0.0;
    float sa = 0.0f;
    #pragma unroll 4
    for (int c = 0; c < EDIM; c += 4) {
        float v0 = p[(size_t)(c + 0) << 10];
        float v1 = p[(size_t)(c + 1) << 10];
        float v2 = p[(size_t)(c + 2) << 10];
        float v3 = p[(size_t)(c + 3) << 10];
        float w0 = v0 * v0, w1 = v1 * v1, w2 = v2 * v2, w3 = v3 * v3;
        s0 += (double)w0; s1 += (double)w1; s2 += (double)w2; s3 += (double)w3;
        sa += fabsf(v0) + fabsf(v1) + fabsf(v2) + fabsf(v3);
    }
    Crow[r] = (float)((s0 + s1) + (s2 + s3));
    // margin M >= 2*ulp(~256..512) + 8*eps_approx. Worst-case need ~7.5e-5; 6x headroom.
    Mrow[r] = 2.5e-4f + 1.0e-6f * sa;
}

// ---------- kernel 1b: z -> Zt[r][k] (row-major, k contiguous), LDS-tiled transpose ----------
__global__ void vq_transpose(const float* __restrict__ z, float* __restrict__ Zt) {
    __shared__ float tile[64][65];
    const int t = threadIdx.x;
    const int ct = blockIdx.x, rt = blockIdx.y;   // ct 0..3, rt 0..255
    const int tr = t & 63, tc = t >> 6;
    #pragma unroll
    for (int i = 0; i < 16; ++i) {
        int c_l = i * 4 + tc;
        int r = rt * 64 + tr;
        int c = ct * 64 + c_l;
        tile[tr][c_l] = z[(((size_t)(r >> 10) * 256 + c) << 10) + (r & 1023)];
    }
    __syncthreads();
    #pragma unroll
    for (int i = 0; i < 16; ++i) {
        int r_l = i * 4 + tc;
        Zt[(size_t)(rt * 64 + r_l) * EDIM + ct * 64 + tr] = tile[r_l][tr];
    }
}

// ---------- kernel 2: 3-term split-bf16 MFMA GEMM; per (row, 128-col blk) max of S ----------
// S = zh.eh + zh.el + zl.eh  ~ exact fp32 dot to ~3e-6 worst case.
__global__ __launch_bounds__(256) void vq_mfma3(
    const float* __restrict__ Zt, const float* __restrict__ cb,
    unsigned int* __restrict__ part)
{
    __shared__ unsigned short Ah[128 * PITCH], Al[128 * PITCH];
    __shared__ unsigned short Bh[128 * PITCH], Bl[128 * PITCH];
    const int t = threadIdx.x;
    const int bx = blockIdx.x;           // col block 0..63
    const int by = blockIdx.y;           // row tile 0..127
    const int row0 = by * 128, col0 = bx * 128;
    const int lane = t & 63, wid = t >> 6;
    const int wr = wid >> 1, wc = wid & 1;
    const int lr = lane & 15, lk = lane >> 4;
    const int kq = t & 15, rr = t >> 4;

    f32x4 acc[4][4];
    #pragma unroll
    for (int i = 0; i < 4; ++i)
        #pragma unroll
        for (int j = 0; j < 4; ++j)
            acc[i][j] = (f32x4){0.f, 0.f, 0.f, 0.f};

    for (int kt = 0; kt < 4; ++kt) {
        if (kt) __syncthreads();          // previous tile's LDS reads done
        #pragma unroll
        for (int p = 0; p < 8; ++p) {
            int rl = p * 16 + rr;
            float4 va = *(const float4*)(Zt + (size_t)(row0 + rl) * EDIM + kt * 64 + kq * 4);
            ushort4 H, L;
            cvt_split4(va, &H, &L);
            *(ushort4*)&Ah[rl * PITCH + kq * 4] = H;
            *(ushort4*)&Al[rl * PITCH + kq * 4] = L;
            float4 vb = *(const float4*)(cb + (size_t)(col0 + rl) * EDIM + kt * 64 + kq * 4);
            cvt_split4(vb, &H, &L);
            *(ushort4*)&Bh[rl * PITCH + kq * 4] = H;
            *(ushort4*)&Bl[rl * PITCH + kq * 4] = L;
        }
        __syncthreads();
        #pragma unroll
        for (int kk = 0; kk < 2; ++kk) {
            bf16x8 ah[4], alo[4], bh[4], blo[4];
            #pragma unroll
            for (int f = 0; f < 4; ++f) {
                int ra = (wr * 64 + f * 16 + lr) * PITCH + kk * 32 + lk * 8;
                ah[f]  = *(const bf16x8*)&Ah[ra];
                alo[f] = *(const bf16x8*)&Al[ra];
                int rb = (wc * 64 + f * 16 + lr) * PITCH + kk * 32 + lk * 8;
                bh[f]  = *(const bf16x8*)&Bh[rb];
                blo[f] = *(const bf16x8*)&Bl[rb];
            }
            #pragma unroll
            for (int fi = 0; fi < 4; ++fi)
                #pragma unroll
                for (int fj = 0; fj < 4; ++fj) {
                    acc[fi][fj] = __builtin_amdgcn_mfma_f32_16x16x32_bf16(ah[fi],  bh[fj],  acc[fi][fj], 0, 0, 0);
                    acc[fi][fj] = __builtin_amdgcn_mfma_f32_16x16x32_bf16(ah[fi],  blo[fj], acc[fi][fj], 0, 0, 0);
                    acc[fi][fj] = __builtin_amdgcn_mfma_f32_16x16x32_bf16(alo[fi], bh[fj],  acc[fi][fj], 0, 0, 0);
                }
        }
    }

    // epilogue: per-row max of S over this block's 128 cols -> part[blk][row] (ordered u32)
    #pragma unroll
    for (int fi = 0; fi < 4; ++fi)
        #pragma unroll
        for (int reg = 0; reg < 4; ++reg) {
            float v = fmaxf(fmaxf(acc[fi][0][reg], acc[fi][1][reg]),
                            fmaxf(acc[fi][2][reg], acc[fi][3][reg]));
            #pragma unroll
            for (int m = 1; m <= 8; m <<= 1) v = fmaxf(v, __shfl_xor(v, m));
            if (lr == 0) {
                int rowg = row0 + wr * 64 + fi * 16 + lk * 4 + reg;
                atomicMax(&part[(size_t)bx * N_ROWS + rowg], f2ord(v));
            }
        }
}

// ---------- kernel 3: qualify blocks per row; build per-block row lists ----------
__global__ void vq_qualify(const unsigned int* __restrict__ part,
                           const float* __restrict__ Mrow,
                           int* __restrict__ counts, int* __restrict__ lists)
{
    int row = blockIdx.x * 256 + threadIdx.x;
    unsigned int umax = 0u;
    for (int b = 0; b < NBLK; ++b) {
        unsigned int u = part[(size_t)b * N_ROWS + row];
        umax = (u > umax) ? u : umax;
    }
    float thr = ord2f(umax) - 0.5f * Mrow[row];
    unsigned int uthr = f2ord(thr);
    for (int b = 0; b < NBLK; ++b)
        if (part[(size_t)b * N_ROWS + row] >= uthr) {
            int pos = atomicAdd(&counts[b], 1);
            lists[b * N_ROWS + pos] = row;
        }
}

// ---------- kernel 4: exact fp32 recheck of qualifying (row, 128-col blk) pairs ----------
// Bit-identical to the original: sequential-k fmaf, d = fl(Crow - 2*acc), (ord,col) atomicMin.
__global__ __launch_bounds__(256) void vq_recheck(
    const float* __restrict__ Zt, const float* __restrict__ cb,
    const float* __restrict__ Crow, const int* __restrict__ counts,
    const int* __restrict__ lists, unsigned long long* __restrict__ keys)
{
    __shared__ float cbl[32][268];   // 268 pad: 67x16B granules -> minimal-phase b128 reads
    __shared__ float zr[8][256];
    const int t = threadIdx.x;
    const int b = blockIdx.x >> 2, sub = blockIdx.x & 3;
    const int count = counts[b];
    if (count == 0) return;
    const int c = t & 31, rsl = t >> 5;

    for (int cq = 0; cq < 4; ++cq) {
        __syncthreads();   // previous quarter's compute done before restaging cbl
        {
            int col = t >> 3, k8 = t & 7;
            const float* src = cb + (size_t)(b * BLKC + cq * 32 + col) * EDIM + k8 * 32;
            #pragma unroll
            for (int j = 0; j < 8; ++j)
                *(float4*)&cbl[col][k8 * 32 + j * 4] = *(const float4*)(src + j * 4);
        }
        __syncthreads();
        for (int i0 = sub * 8; i0 < count; i0 += 32) {
            int rli = i0 + rsl;
            bool valid = rli < count;
            int row = lists[b * N_ROWS + (valid ? rli : (count - 1))];
            __syncthreads();   // protect zr reuse across iterations
            {
                int rs = t >> 5, kk = t & 31;
                int rli2 = i0 + rs;
                int row2 = lists[b * N_ROWS + ((rli2 < count) ? rli2 : (count - 1))];
                #pragma unroll
                for (int j = 0; j < 8; ++j)
                    zr[rs][j * 32 + kk] = Zt[(size_t)row2 * EDIM + j * 32 + kk];
            }
            __syncthreads();
            float acc = 0.0f;
            #pragma unroll 8
            for (int k = 0; k < EDIM; k += 4) {
                float4 bv = *(const float4*)&cbl[c][k];
                float4 zv = *(const float4*)&zr[rsl][k];
                acc = fmaf(zv.x, bv.x, acc);
                acc = fmaf(zv.y, bv.y, acc);
                acc = fmaf(zv.z, bv.z, acc);
                acc = fmaf(zv.w, bv.w, acc);
            }
            int col = b * BLKC + cq * 32 + c;
            float d = Crow[row] - 2.0f * acc;
            unsigned long long key =
                ((unsigned long long)f2ord(d) << 32) | (unsigned int)col;
            #pragma unroll
            for (int m = 1; m <= 16; m <<= 1) {
                unsigned long long o = shfl_xor_u64(key, m);
                key = (o < key) ? o : key;
            }
            if (c == 0 && valid) atomicMin(&keys[row], key);
        }
    }
}

// ---------- kernel 5: gather quant, straight-through, loss partials, indices ----------
__global__ void vq_finalize(const float* __restrict__ z, const float* __restrict__ cb,
                            const unsigned long long* __restrict__ keys,
                            float* __restrict__ out_q, float* __restrict__ out_idx,
                            double* __restrict__ accum)
{
    int o  = blockIdx.x * 256 + threadIdx.x;
    int b  = o >> 18;
    int cc = (o >> 10) & 255;
    int hw = o & 1023;
    int r  = (b << 10) | hw;
    unsigned int idx = (unsigned int)(keys[r] & 0xffffffffull);
    float zv = z[o];
    float q  = cb[(size_t)idx * EDIM + cc];
    float d  = q - zv;
    out_q[o] = zv + d;
    if (cc == 0) out_idx[r] = (float)idx;

    double p = (double)d * (double)d;
    #pragma unroll
    for (int m = 32; m >= 1; m >>= 1) p += __shfl_down(p, m);
    __shared__ double wsum[4];
    if ((threadIdx.x & 63) == 0) wsum[threadIdx.x >> 6] = p;
    __syncthreads();
    if (threadIdx.x == 0)
        atomicAdd(accum, (wsum[0] + wsum[1]) + (wsum[2] + wsum[3]));
}

// ---------- kernel 6: loss = 1.25 * mean((q-z)^2) ----------
__global__ void vq_loss(const double* __restrict__ accum, float* __restrict__ out_loss) {
    out_loss[0] = (float)(1.25 * (accum[0] / (double)QELEMS));
}

// ---------- launcher ----------
extern "C" void kernel_launch(void* const* d_in, const int* in_sizes, int n_in,
                              void* d_out, int out_size, void* d_ws, size_t ws_size,
                              hipStream_t stream) {
    const float* z  = (const float*)d_in[0];   // [16,256,32,32]
    const float* cb = (const float*)d_in[1];   // [8192,256]
    float* out = (float*)d_out;                // quant | loss | indices

    // workspace layout (aligned, ~24.3 MB total)
    char* ws = (char*)d_ws;
    unsigned long long* keys = (unsigned long long*)(ws + 0);          // 131072
    float*  Crow  = (float*)(ws + 131072);                             // 65536
    float*  Mrow  = (float*)(ws + 196608);                             // 65536
    double* accum = (double*)(ws + 262144);                            // 8 (pad to 262400)
    int*    counts = (int*)(ws + 262400);                              // 256 (pad to 263168)
    unsigned int* part = (unsigned int*)(ws + 263168);                 // 64*16384*4 = 4 MB
    int*    lists = (int*)(ws + 4457472);                              // 64*16384*4 = 4 MB
    float*  Zt    = (float*)(ws + 8651776);                            // 16 MB

    hipMemsetAsync(keys, 0xFF, (size_t)N_ROWS * 8, stream);
    hipMemsetAsync(accum, 0, 8, stream);
    hipMemsetAsync(counts, 0, 256, stream);
    hipMemsetAsync(part, 0, (size_t)NBLK * N_ROWS * 4, stream);        // ordered(-inf) = 0

    vq_rownorm  <<<N_ROWS / 256, 256, 0, stream>>>(z, Crow, Mrow);
    vq_transpose<<<dim3(4, 256), 256, 0, stream>>>(z, Zt);
    vq_mfma3    <<<dim3(NBLK, N_ROWS / 128), 256, 0, stream>>>(Zt, cb, part);
    vq_qualify  <<<N_ROWS / 256, 256, 0, stream>>>(part, Mrow, counts, lists);
    vq_recheck  <<<NBLK * 4, 256, 0, stream>>>(Zt, cb, Crow, counts, lists, keys);
    vq_finalize <<<QELEMS / 256, 256, 0, stream>>>(z, cb, keys, out, out + QELEMS + 1, accum);
    vq_loss     <<<1, 1, 0, stream>>>(accum, out + QELEMS);
}

// Round 2
// 270.542 us; speedup vs baseline: 3.7500x; 3.0807x over previous
//
#include <hip/hip_runtime.h>
#include <stdint.h>

#define N_ROWS 16384   // 16 * 32 * 32
#define N_E    8192
#define EDIM   256
#define QELEMS 4194304 // 16*256*32*32
#define NCHUNK 256     // 8192 / 32 col chunks

using f32x4  = __attribute__((ext_vector_type(4))) float;
using bf16x8 = __attribute__((ext_vector_type(8))) short;

// ---------- helpers ----------
__device__ __forceinline__ unsigned int f2ord(float f) {
    unsigned int u = __float_as_uint(f);
    return (u & 0x80000000u) ? ~u : (u | 0x80000000u);
}
__device__ __forceinline__ float ord2f(unsigned int o) {
    unsigned int u = (o & 0x80000000u) ? (o & 0x7fffffffu) : ~o;
    return __uint_as_float(u);
}
__device__ __forceinline__ unsigned long long shfl_xor_u64(unsigned long long v, int m) {
    int lo = __shfl_xor((int)(unsigned int)(v & 0xffffffffull), m);
    int hi = __shfl_xor((int)(unsigned int)(v >> 32), m);
    return ((unsigned long long)(unsigned int)hi << 32) | (unsigned long long)(unsigned int)lo;
}
// round-to-nearest-even float -> bf16 bits (inputs finite, no NaN)
__device__ __forceinline__ unsigned short f2bf(float f) {
    unsigned int u = __float_as_uint(f);
    u += 0x7fffu + ((u >> 16) & 1u);
    return (unsigned short)(u >> 16);
}
__device__ __forceinline__ float bf2f(unsigned short h) {
    return __uint_as_float((unsigned int)h << 16);
}
__device__ __forceinline__ void cvt_split4(float4 v, ushort4* H, ushort4* L) {
    unsigned short h0 = f2bf(v.x), h1 = f2bf(v.y), h2 = f2bf(v.z), h3 = f2bf(v.w);
    H->x = h0; H->y = h1; H->z = h2; H->w = h3;
    L->x = f2bf(v.x - bf2f(h0));
    L->y = f2bf(v.y - bf2f(h1));
    L->z = f2bf(v.z - bf2f(h2));
    L->w = f2bf(v.w - bf2f(h3));
}
// async global->LDS, 16B per lane; lds dest must be wave-uniform (HW adds lane*16)
__device__ __forceinline__ void gload_lds16(const char* g, char* l) {
    __builtin_amdgcn_global_load_lds(
        (const __attribute__((address_space(1))) void*)g,
        (__attribute__((address_space(3))) void*)l, 16, 0, 0);
}

// ---------- kernel 1: row norms (UNCHANGED math -> bit-identical Crow) + margin ----------
__global__ void vq_rownorm(const float* __restrict__ z, float* __restrict__ Crow,
                           float* __restrict__ Mrow) {
    int r = blockIdx.x * blockDim.x + threadIdx.x;
    if (r >= N_ROWS) return;
    int b = r >> 10, hw = r & 1023;
    const float* p = z + ((size_t)b << 18) + hw;
    double s0 = 0.0, s1 = 0.0, s2 = 0.0, s3 = 0.0;
    float sa = 0.0f;
    #pragma unroll 4
    for (int c = 0; c < EDIM; c += 4) {
        float v0 = p[(size_t)(c + 0) << 10];
        float v1 = p[(size_t)(c + 1) << 10];
        float v2 = p[(size_t)(c + 2) << 10];
        float v3 = p[(size_t)(c + 3) << 10];
        float w0 = v0 * v0, w1 = v1 * v1, w2 = v2 * v2, w3 = v3 * v3;
        s0 += (double)w0; s1 += (double)w1; s2 += (double)w2; s3 += (double)w3;
        sa += fabsf(v0) + fabsf(v1) + fabsf(v2) + fabsf(v3);
    }
    Crow[r] = (float)((s0 + s1) + (s2 + s3));
    // need 0.5*M >= ulpD-window(4e-5) + 2*E, E ~= 2.43e-7*sum|z|  ->  2x headroom:
    Mrow[r] = 1.0e-4f + 2.0e-6f * sa;
}

// ---------- kernel 1b: z -> Zt[r][k] f32 + Zth bf16-hi in swizzled chunk layout ----------
// Zth chunk layout: [rtile(128r)][ktile(64k)] 16KB chunks; within: granule(16B = 8 bf16,
// k-contig) at index rl*8 + (k8 ^ (rl&7)).
__global__ void vq_transpose(const float* __restrict__ z, float* __restrict__ Zt,
                             unsigned short* __restrict__ Zth) {
    __shared__ float tile[64][65];
    const int t = threadIdx.x;
    const int ct = blockIdx.x, rt = blockIdx.y;   // ct 0..3 (64k), rt 0..255 (64r)
    const int tr = t & 63, tc = t >> 6;
    #pragma unroll
    for (int i = 0; i < 16; ++i) {
        int c_l = i * 4 + tc;
        int r = rt * 64 + tr;
        int c = ct * 64 + c_l;
        tile[tr][c_l] = z[(((size_t)(r >> 10) * 256 + c) << 10) + (r & 1023)];
    }
    __syncthreads();
    const int k8 = tr >> 3, k0 = tr & 7;
    #pragma unroll
    for (int i = 0; i < 16; ++i) {
        int r_l = i * 4 + tc;
        int r = rt * 64 + r_l;
        float v = tile[r_l][tr];
        Zt[(size_t)r * EDIM + ct * 64 + tr] = v;
        int rl = r & 127;
        size_t chunk = ((size_t)(r >> 7) * 4 + ct) * 8192;
        Zth[chunk + (size_t)(rl * 8 + (k8 ^ (rl & 7))) * 8 + k0] = f2bf(v);
    }
}

// ---------- kernel 1c: cb -> cbh/cbl bf16 in swizzled chunk layout ----------
__global__ void vq_cbsplit(const float* __restrict__ cb, unsigned short* __restrict__ cbh,
                           unsigned short* __restrict__ cbl) {
    const int t = threadIdx.x;
    const int nt = blockIdx.x, kt = blockIdx.y;   // 64 x 4
    const int nl0 = t >> 4, kq = t & 15;
    const size_t chunk = ((size_t)nt * 4 + kt) * 8192;
    const int k8 = kq >> 1, k0 = (kq & 1) * 4;
    #pragma unroll
    for (int i = 0; i < 8; ++i) {
        int nl = i * 16 + nl0;
        float4 v = *(const float4*)(cb + (size_t)(nt * 128 + nl) * EDIM + kt * 64 + kq * 4);
        ushort4 H, L;
        cvt_split4(v, &H, &L);
        size_t addr = chunk + (size_t)(nl * 8 + (k8 ^ (nl & 7))) * 8 + k0;
        *(ushort4*)(cbh + addr) = H;
        *(ushort4*)(cbl + addr) = L;
    }
}

// ---------- kernel 2: 2-term split-bf16 MFMA GEMM; per (row, 32-col chunk) max of S ----------
// S = zh.(eh + el); |S - Sfma| <= ~2.43e-7 * sum|z|  (covered by Mrow).
__global__ __launch_bounds__(256, 3) void vq_mfma3(
    const unsigned short* __restrict__ Zth, const unsigned short* __restrict__ cbh,
    const unsigned short* __restrict__ cbl, unsigned int* __restrict__ part)
{
    __shared__ __align__(16) short Ah[8192];   // 128 x 64 bf16, swizzled granules
    __shared__ __align__(16) short Bh[8192];
    __shared__ __align__(16) short Bl[8192];
    const int t = threadIdx.x;
    const int bx = blockIdx.x;           // col block 0..63 (128 cols)
    const int by = blockIdx.y;           // row tile 0..127 (128 rows)
    const int row0 = by * 128;
    const int lane = t & 63, w = t >> 6;
    const int wr = w >> 1, wc = w & 1;
    const int lr = lane & 15, lk = lane >> 4;
    const int lr7 = lr & 7;

    const char* gA  = (const char*)Zth + ((size_t)by * 4) * 16384;
    const char* gBh = (const char*)cbh + ((size_t)bx * 4) * 16384;
    const char* gBl = (const char*)cbl + ((size_t)bx * 4) * 16384;
    char* lA  = (char*)Ah;
    char* lBh = (char*)Bh;
    char* lBl = (char*)Bl;

    f32x4 acc[4][4];
    #pragma unroll
    for (int i = 0; i < 4; ++i)
        #pragma unroll
        for (int j = 0; j < 4; ++j)
            acc[i][j] = (f32x4){0.f, 0.f, 0.f, 0.f};

    for (int kt = 0; kt < 4; ++kt) {
        if (kt) __syncthreads();          // prev tile's LDS reads done
        #pragma unroll
        for (int j = 0; j < 4; ++j) {
            int ci = (w * 4 + j) * 1024;  // 1KB chunk byte offset
            gload_lds16(gA  + kt * 16384 + ci + lane * 16, lA  + ci);
            gload_lds16(gBh + kt * 16384 + ci + lane * 16, lBh + ci);
            gload_lds16(gBl + kt * 16384 + ci + lane * 16, lBl + ci);
        }
        __syncthreads();                  // vmcnt(0) drain + barrier
        #pragma unroll
        for (int kk = 0; kk < 2; ++kk) {
            bf16x8 ah[4], bh[4], bl[4];
            #pragma unroll
            for (int f = 0; f < 4; ++f) {
                int sA = (kk * 4 + lk) ^ lr7;
                int ra = ((wr * 64 + f * 16 + lr) * 8 + sA) * 8;   // shorts
                ah[f] = *(const bf16x8*)&Ah[ra];
                int rb = ((wc * 64 + f * 16 + lr) * 8 + sA) * 8;
                bh[f] = *(const bf16x8*)&Bh[rb];
                bl[f] = *(const bf16x8*)&Bl[rb];
            }
            #pragma unroll
            for (int fi = 0; fi < 4; ++fi)
                #pragma unroll
                for (int fj = 0; fj < 4; ++fj) {
                    acc[fi][fj] = __builtin_amdgcn_mfma_f32_16x16x32_bf16(ah[fi], bh[fj], acc[fi][fj], 0, 0, 0);
                    acc[fi][fj] = __builtin_amdgcn_mfma_f32_16x16x32_bf16(ah[fi], bl[fj], acc[fi][fj], 0, 0, 0);
                }
        }
    }

    // epilogue: per-row max over each 32-col chunk -> plain store (each entry written once)
    #pragma unroll
    for (int fi = 0; fi < 4; ++fi)
        #pragma unroll
        for (int fjp = 0; fjp < 2; ++fjp)
            #pragma unroll
            for (int reg = 0; reg < 4; ++reg) {
                float v = fmaxf(acc[fi][2 * fjp][reg], acc[fi][2 * fjp + 1][reg]);
                #pragma unroll
                for (int m = 1; m <= 8; m <<= 1) v = fmaxf(v, __shfl_xor(v, m));
                if (lr == 0) {
                    int rowg = row0 + wr * 64 + fi * 16 + lk * 4 + reg;
                    int chnk = bx * 4 + wc * 2 + fjp;
                    part[(size_t)chnk * N_ROWS + rowg] = f2ord(v);
                }
            }
}

// ---------- kernel 3: per-row threshold ----------
__global__ void vq_qualify(const unsigned int* __restrict__ part,
                           const float* __restrict__ Mrow,
                           unsigned int* __restrict__ uthr)
{
    int row = blockIdx.x * 256 + threadIdx.x;
    unsigned int umax = 0u;
    for (int c = 0; c < NCHUNK; ++c) {
        unsigned int u = part[(size_t)c * N_ROWS + row];
        umax = (u > umax) ? u : umax;
    }
    float thr = ord2f(umax) - 0.5f * Mrow[row];
    uthr[row] = f2ord(thr);
}

// ---------- kernel 4: exact fp32 recheck of qualifying (row, 32-col chunk) pairs ----------
// Bit-identical decision path: sequential-k fmaf, d = fl(Crow - 2*acc), (ord,col) atomicMin.
__global__ __launch_bounds__(256, 1) void vq_recheck(
    const float* __restrict__ Zt, const float* __restrict__ cb,
    const float* __restrict__ Crow, const unsigned int* __restrict__ part,
    const unsigned int* __restrict__ uthr, unsigned long long* __restrict__ keys)
{
    __shared__ float cbt[32 * 256];      // 32 cols x 256 k, granule-XOR swizzled (32KB)
    __shared__ int lrows[N_ROWS];        // 64KB worst case
    __shared__ int lcount;
    const int t = threadIdx.x;
    const int chunk = blockIdx.x;        // 0..255
    if (t == 0) lcount = 0;
    // stage cb chunk: col c at granule (k4 ^ (c&7))
    {
        int col = t >> 3, kq = t & 7;
        const float* src = cb + (size_t)(chunk * 32 + col) * EDIM + kq * 32;
        #pragma unroll
        for (int j = 0; j < 8; ++j) {
            float4 v = *(const float4*)(src + j * 4);
            int k4 = kq * 8 + j;
            *(float4*)&cbt[col * 256 + (((unsigned)(k4 ^ (col & 7))) << 2)] = v;
        }
    }
    __syncthreads();
    // phase 1: scan all rows, append qualifying to LDS list
    for (int r0 = 0; r0 < N_ROWS; r0 += 256) {
        int row = r0 + t;
        if (part[(size_t)chunk * N_ROWS + row] >= uthr[row]) {
            int pos = atomicAdd(&lcount, 1);
            lrows[pos] = row;
        }
    }
    __syncthreads();
    const int cnt = lcount;
    // phase 2: 8 col-groups x 32 rows per pass; 4 cols/thread (cg, cg+8, cg+16, cg+24)
    const int cg = t & 7, rl = t >> 3;
    for (int i0 = 0; i0 < cnt; i0 += 32) {
        int li = i0 + rl;
        bool valid = li < cnt;
        int row = lrows[valid ? li : (cnt - 1)];
        const float* zp = Zt + (size_t)row * EDIM;
        float a0 = 0.f, a1 = 0.f, a2 = 0.f, a3 = 0.f;
        #pragma unroll 8
        for (int k4 = 0; k4 < 64; ++k4) {
            float4 zv = *(const float4*)(zp + k4 * 4);
            int g = ((unsigned)(k4 ^ cg)) << 2;   // same XOR key for all 4 cols (stride 8)
            float4 b0 = *(const float4*)&cbt[(cg +  0) * 256 + g];
            float4 b1 = *(const float4*)&cbt[(cg +  8) * 256 + g];
            float4 b2 = *(const float4*)&cbt[(cg + 16) * 256 + g];
            float4 b3 = *(const float4*)&cbt[(cg + 24) * 256 + g];
            a0 = fmaf(zv.x, b0.x, a0); a0 = fmaf(zv.y, b0.y, a0);
            a0 = fmaf(zv.z, b0.z, a0); a0 = fmaf(zv.w, b0.w, a0);
            a1 = fmaf(zv.x, b1.x, a1); a1 = fmaf(zv.y, b1.y, a1);
            a1 = fmaf(zv.z, b1.z, a1); a1 = fmaf(zv.w, b1.w, a1);
            a2 = fmaf(zv.x, b2.x, a2); a2 = fmaf(zv.y, b2.y, a2);
            a2 = fmaf(zv.z, b2.z, a2); a2 = fmaf(zv.w, b2.w, a2);
            a3 = fmaf(zv.x, b3.x, a3); a3 = fmaf(zv.y, b3.y, a3);
            a3 = fmaf(zv.z, b3.z, a3); a3 = fmaf(zv.w, b3.w, a3);
        }
        float Cr = Crow[row];
        int colbase = chunk * 32;
        unsigned long long best;
        {
            unsigned long long k0 = ((unsigned long long)f2ord(Cr - 2.0f * a0) << 32) | (unsigned int)(colbase + cg);
            unsigned long long k1 = ((unsigned long long)f2ord(Cr - 2.0f * a1) << 32) | (unsigned int)(colbase + cg + 8);
            unsigned long long k2 = ((unsigned long long)f2ord(Cr - 2.0f * a2) << 32) | (unsigned int)(colbase + cg + 16);
            unsigned long long k3 = ((unsigned long long)f2ord(Cr - 2.0f * a3) << 32) | (unsigned int)(colbase + cg + 24);
            best = (k0 < k1) ? k0 : k1;
            best = (k2 < best) ? k2 : best;
            best = (k3 < best) ? k3 : best;
        }
        #pragma unroll
        for (int m = 1; m <= 4; m <<= 1) {
            unsigned long long o = shfl_xor_u64(best, m);
            best = (o < best) ? o : best;
        }
        if (cg == 0 && valid) atomicMin(&keys[row], best);
    }
}

// ---------- kernel 5: gather quant via row-tiled LDS, straight-through, loss, indices ----------
__global__ void vq_finalize(const float* __restrict__ z, const float* __restrict__ cb,
                            const unsigned long long* __restrict__ keys,
                            float* __restrict__ out_q, float* __restrict__ out_idx,
                            double* __restrict__ accum)
{
    __shared__ float qld[64][257];
    __shared__ int sIdx[64];
    const int t = threadIdx.x;
    const int r0 = blockIdx.x * 64;            // 64 rows, same b
    const int b = r0 >> 10, hw0 = r0 & 1023;
    if (t < 64) {
        unsigned int idx = (unsigned int)(keys[r0 + t] & 0xffffffffull);
        sIdx[t] = (int)idx;
        out_idx[r0 + t] = (float)idx;
    }
    __syncthreads();
    // stage 64 cb rows: 4 threads/row, 64B segments
    {
        int i = t >> 2, q4 = t & 3;
        const float* src = cb + (size_t)sIdx[i] * EDIM;
        #pragma unroll
        for (int j = 0; j < 16; ++j)
            *(float4*)&qld[i][j * 16 + q4 * 4] = *(const float4*)(src + j * 16 + q4 * 4);
    }
    __syncthreads();
    const int hw_l = t & 63, cg = t >> 6;
    double p = 0.0;
    #pragma unroll 4
    for (int j = 0; j < 64; ++j) {
        int c = cg * 64 + j;
        float q  = qld[hw_l][c];
        size_t o = (((size_t)(b * 256 + c)) << 10) + hw0 + hw_l;
        float zv = z[o];
        float d  = q - zv;                 // fl(q - z)
        out_q[o] = zv + d;                 // exact straight-through
        p += (double)d * (double)d;
    }
    #pragma unroll
    for (int m = 32; m >= 1; m >>= 1) p += __shfl_down(p, m);
    __shared__ double wsum[4];
    if ((t & 63) == 0) wsum[t >> 6] = p;
    __syncthreads();
    if (t == 0)
        atomicAdd(accum, (wsum[0] + wsum[1]) + (wsum[2] + wsum[3]));
}

// ---------- kernel 6: loss = 1.25 * mean((q-z)^2) ----------
__global__ void vq_loss(const double* __restrict__ accum, float* __restrict__ out_loss) {
    out_loss[0] = (float)(1.25 * (accum[0] / (double)QELEMS));
}

// ---------- launcher ----------
extern "C" void kernel_launch(void* const* d_in, const int* in_sizes, int n_in,
                              void* d_out, int out_size, void* d_ws, size_t ws_size,
                              hipStream_t stream) {
    const float* z  = (const float*)d_in[0];   // [16,256,32,32]
    const float* cb = (const float*)d_in[1];   // [8192,256]
    float* out = (float*)d_out;                // quant | loss | indices

    // workspace layout (~48.3 MB)
    char* ws = (char*)d_ws;
    unsigned long long* keys = (unsigned long long*)(ws + 0);          // 131072
    float*  Crow  = (float*)(ws + 131072);                             // 65536
    float*  Mrow  = (float*)(ws + 196608);                             // 65536
    unsigned int* uthr = (unsigned int*)(ws + 262144);                 // 65536
    double* accum = (double*)(ws + 327680);                            // 8 (pad to 331776)
    unsigned int* part = (unsigned int*)(ws + 331776);                 // 256*16384*4 = 16 MB
    float*  Zt    = (float*)(ws + 17108992);                           // 16 MB
    unsigned short* Zth = (unsigned short*)(ws + 33886208);            // 8 MB
    unsigned short* cbh = (unsigned short*)(ws + 42274816);            // 4 MB
    unsigned short* cbl = (unsigned short*)(ws + 46469120);            // 4 MB -> end 50663424

    hipMemsetAsync(keys, 0xFF, (size_t)N_ROWS * 8, stream);
    hipMemsetAsync(accum, 0, 8, stream);

    vq_rownorm  <<<N_ROWS / 256, 256, 0, stream>>>(z, Crow, Mrow);
    vq_transpose<<<dim3(4, 256), 256, 0, stream>>>(z, Zt, Zth);
    vq_cbsplit  <<<dim3(64, 4), 256, 0, stream>>>(cb, cbh, cbl);
    vq_mfma3    <<<dim3(64, 128), 256, 0, stream>>>(Zth, cbh, cbl, part);
    vq_qualify  <<<N_ROWS / 256, 256, 0, stream>>>(part, Mrow, uthr);
    vq_recheck  <<<NCHUNK, 256, 0, stream>>>(Zt, cb, Crow, part, uthr, keys);
    vq_finalize <<<N_ROWS / 64, 256, 0, stream>>>(z, cb, keys, out, out + QELEMS + 1, accum);
    vq_loss     <<<1, 1, 0, stream>>>(accum, out + QELEMS);
}